// Round 1
// baseline (985.752 us; speedup 1.0000x reference)
//
#include <hip/hip_runtime.h>
#include <hip/hip_bf16.h>
#include <stdint.h>

#define N_DIM 4
#define FIN 32
#define KORD 4
#define FOUT 64
#define ROWLEN 128   // FIN * N_DIM

// ---------------------------------------------------------------------------
// 1. Transpose x[N][M][Fin] -> T0[m][f*4+n]  (float4 per (m,f))
// ---------------------------------------------------------------------------
__global__ void transpose_kernel(const float* __restrict__ x,
                                 float* __restrict__ T0, int MF) {
  int i = blockIdx.x * blockDim.x + threadIdx.x;
  if (i >= MF) return;
  float4 v;
  v.x = x[i];
  v.y = x[(size_t)MF + i];
  v.z = x[(size_t)2 * MF + i];
  v.w = x[(size_t)3 * MF + i];
  reinterpret_cast<float4*>(T0)[i] = v;
}

// ---------------------------------------------------------------------------
// 2. CSR build: histogram -> exclusive scan -> scatter
// ---------------------------------------------------------------------------
__global__ void hist_kernel(const int* __restrict__ rows,
                            int* __restrict__ cursor, int E) {
  int e = blockIdx.x * blockDim.x + threadIdx.x;
  if (e < E) atomicAdd(&cursor[rows[e]], 1);
}

__global__ void scan_kernel(int* __restrict__ cursor,
                            int* __restrict__ row_start, int M) {
  __shared__ int wsum[16];
  __shared__ int carry;
  __shared__ int total;
  if (threadIdx.x == 0) carry = 0;
  __syncthreads();
  int nchunk = (M + 1023) / 1024;
  for (int chunk = 0; chunk < nchunk; ++chunk) {
    int i = chunk * 1024 + (int)threadIdx.x;
    int v = (i < M) ? cursor[i] : 0;
    int lane = threadIdx.x & 63;
    int wid = threadIdx.x >> 6;
    int s = v;
#pragma unroll
    for (int off = 1; off < 64; off <<= 1) {
      int u = __shfl_up(s, off);
      if (lane >= off) s += u;
    }
    if (lane == 63) wsum[wid] = s;
    __syncthreads();
    if (threadIdx.x == 0) {
      int run = 0;
#pragma unroll
      for (int w = 0; w < 16; ++w) { int t = wsum[w]; wsum[w] = run; run += t; }
      total = run;
    }
    __syncthreads();
    int excl = carry + wsum[wid] + (s - v);
    if (i < M) { row_start[i] = excl; cursor[i] = excl; }
    __syncthreads();               // everyone done reading carry/wsum
    if (threadIdx.x == 0) carry += total;
    __syncthreads();
  }
  if (threadIdx.x == 0) row_start[M] = carry;
}

__global__ void scatter_kernel(const int* __restrict__ rows,
                               const int* __restrict__ cols,
                               const float* __restrict__ vals,
                               int* __restrict__ cursor,
                               int* __restrict__ csr_col,
                               float* __restrict__ csr_val, int E) {
  int e = blockIdx.x * blockDim.x + threadIdx.x;
  if (e >= E) return;
  int r = rows[e];
  int p = atomicAdd(&cursor[r], 1);
  csr_col[p] = cols[e];
  csr_val[p] = vals[e];
}

// ---------------------------------------------------------------------------
// 3. SpMM (wave per row):  dst[m,:] = alpha*Sum_e val*src[col,:]
//                                   + beta*src[m,:] + gamma*prev[m,:]
// ---------------------------------------------------------------------------
__global__ void spmm_kernel(const float* __restrict__ src,
                            const float* __restrict__ prev,
                            float* __restrict__ dst,
                            const int* __restrict__ row_start,
                            const int* __restrict__ csr_col,
                            const float* __restrict__ csr_val,
                            int M, float alpha, float beta, float gamma) {
  int gw = (int)((blockIdx.x * blockDim.x + threadIdx.x) >> 6);
  int lane = threadIdx.x & 63;
  if (gw >= M) return;
  int s = row_start[gw];
  int epos = row_start[gw + 1];
  float2 acc = make_float2(0.f, 0.f);
  for (int j = s; j < epos; ++j) {
    int c = csr_col[j];
    float v = csr_val[j];
    float2 a = reinterpret_cast<const float2*>(src + (size_t)c * ROWLEN)[lane];
    acc.x += v * a.x;
    acc.y += v * a.y;
  }
  float2 sv = reinterpret_cast<const float2*>(src + (size_t)gw * ROWLEN)[lane];
  acc.x = alpha * acc.x + beta * sv.x;
  acc.y = alpha * acc.y + beta * sv.y;
  if (prev) {
    float2 pv = reinterpret_cast<const float2*>(prev + (size_t)gw * ROWLEN)[lane];
    acc.x += gamma * pv.x;
    acc.y += gamma * pv.y;
  }
  reinterpret_cast<float2*>(dst + (size_t)gw * ROWLEN)[lane] = acc;
}

// ---------------------------------------------------------------------------
// 4. Final GEMM: out[n*M+m, fo] = Sum_{f,k} Tk[m, f*4+n] * W[f*4+k, fo]
//    Block = 16 vertices (64 xs-rows). X staged to LDS [64][129] (pad ->
//    2-way-max bank aliasing on both stage-writes and fragment reads).
//    W (32 KB) read from L1/L2. 4 rows x 4 fo register tile per thread.
// ---------------------------------------------------------------------------
__global__ __launch_bounds__(256) void gemm_kernel(const float* __restrict__ Tbase,
                                                   const float* __restrict__ W,
                                                   float* __restrict__ out, int M) {
  __shared__ float Xl[64 * 129];
  int m0 = blockIdx.x * 16;
  size_t MR = (size_t)M * ROWLEN;
  // stage: Xl[row=mv*4+n][r=f*4+k] = Tk[m0+mv, f*4+n]
  for (int i = threadIdx.x; i < 8192; i += 256) {
    int k = i >> 11;
    int rem = i & 2047;
    int mv = rem >> 7;
    int c = rem & 127;          // c = f*4 + n
    int m = m0 + mv;
    float v = (m < M) ? Tbase[(size_t)k * MR + (size_t)m * ROWLEN + c] : 0.f;
    int row = mv * 4 + (c & 3);
    int r = (c & ~3) | k;
    Xl[row * 129 + r] = v;
  }
  __syncthreads();

  int fo0 = ((threadIdx.x >> 4) & 15) << 2;  // 0..60
  int row0 = (threadIdx.x & 15) << 2;        // 0..60
  float4 a0 = make_float4(0.f, 0.f, 0.f, 0.f);
  float4 a1 = a0, a2 = a0, a3 = a0;
#pragma unroll 4
  for (int r = 0; r < 128; ++r) {
    float4 w4 = *reinterpret_cast<const float4*>(&W[r * FOUT + fo0]);
    float t0 = Xl[(row0 + 0) * 129 + r];
    float t1 = Xl[(row0 + 1) * 129 + r];
    float t2 = Xl[(row0 + 2) * 129 + r];
    float t3 = Xl[(row0 + 3) * 129 + r];
    a0.x += t0 * w4.x; a0.y += t0 * w4.y; a0.z += t0 * w4.z; a0.w += t0 * w4.w;
    a1.x += t1 * w4.x; a1.y += t1 * w4.y; a1.z += t1 * w4.z; a1.w += t1 * w4.w;
    a2.x += t2 * w4.x; a2.y += t2 * w4.y; a2.z += t2 * w4.z; a2.w += t2 * w4.w;
    a3.x += t3 * w4.x; a3.y += t3 * w4.y; a3.z += t3 * w4.z; a3.w += t3 * w4.w;
  }

  {
    int row = row0;
    int m = m0 + (row >> 2);
    int n = row & 3;
    if (m < M) *reinterpret_cast<float4*>(&out[((size_t)n * M + m) * FOUT + fo0]) = a0;
  }
  {
    int row = row0 + 1;
    int m = m0 + (row >> 2);
    int n = row & 3;
    if (m < M) *reinterpret_cast<float4*>(&out[((size_t)n * M + m) * FOUT + fo0]) = a1;
  }
  {
    int row = row0 + 2;
    int m = m0 + (row >> 2);
    int n = row & 3;
    if (m < M) *reinterpret_cast<float4*>(&out[((size_t)n * M + m) * FOUT + fo0]) = a2;
  }
  {
    int row = row0 + 3;
    int m = m0 + (row >> 2);
    int n = row & 3;
    if (m < M) *reinterpret_cast<float4*>(&out[((size_t)n * M + m) * FOUT + fo0]) = a3;
  }
}

// ---------------------------------------------------------------------------
extern "C" void kernel_launch(void* const* d_in, const int* in_sizes, int n_in,
                              void* d_out, int out_size, void* d_ws, size_t ws_size,
                              hipStream_t stream) {
  const float* x        = (const float*)d_in[0];
  const float* edge_vals = (const float*)d_in[1];
  const float* W        = (const float*)d_in[2];
  const int* edge_rows  = (const int*)d_in[3];
  const int* edge_cols  = (const int*)d_in[4];
  float* out = (float*)d_out;

  int M = in_sizes[0] / (N_DIM * FIN);
  int E = in_sizes[1];
  int MF = M * FIN;

  char* ws = (char*)d_ws;
  size_t tsz = (size_t)M * ROWLEN * sizeof(float);
  float* Tbase = (float*)ws;
  char* p = ws + 4 * tsz;
  int* row_start = (int*)p;  p += (size_t)(M + 1) * sizeof(int);
  int* cursor    = (int*)p;  p += (size_t)M * sizeof(int);
  int* csr_col   = (int*)p;  p += (size_t)E * sizeof(int);
  float* csr_val = (float*)p;

  float* T0 = Tbase;
  float* T1 = Tbase + (size_t)M * ROWLEN;
  float* T2 = T1 + (size_t)M * ROWLEN;
  float* T3 = T2 + (size_t)M * ROWLEN;

  hipMemsetAsync(cursor, 0, (size_t)M * sizeof(int), stream);

  transpose_kernel<<<(MF + 255) / 256, 256, 0, stream>>>(x, T0, MF);
  hist_kernel<<<(E + 255) / 256, 256, 0, stream>>>(edge_rows, cursor, E);
  scan_kernel<<<1, 1024, 0, stream>>>(cursor, row_start, M);
  scatter_kernel<<<(E + 255) / 256, 256, 0, stream>>>(edge_rows, edge_cols, edge_vals,
                                                      cursor, csr_col, csr_val, E);

  int spmm_blocks = (M + 3) / 4;  // wave per row, 4 waves/block
  spmm_kernel<<<spmm_blocks, 256, 0, stream>>>(T0, nullptr, T1, row_start, csr_col,
                                               csr_val, M, 1.f, -1.f, 0.f);
  spmm_kernel<<<spmm_blocks, 256, 0, stream>>>(T1, T0, T2, row_start, csr_col,
                                               csr_val, M, 2.f, -2.f, -1.f);
  spmm_kernel<<<spmm_blocks, 256, 0, stream>>>(T2, T1, T3, row_start, csr_col,
                                               csr_val, M, 2.f, -2.f, -1.f);

  gemm_kernel<<<(M + 15) / 16, 256, 0, stream>>>(Tbase, W, out, M);
}

// Round 2
// 753.551 us; speedup vs baseline: 1.3081x; 1.3081x over previous
//
#include <hip/hip_runtime.h>
#include <hip/hip_bf16.h>
#include <stdint.h>

#define N_DIM 4
#define FIN 32
#define KORD 4
#define FOUT 64
#define ROWLEN 128   // FIN * N_DIM

// ---------------------------------------------------------------------------
// 1. Transpose x[N][M][Fin] -> T0[m][f*4+n]  (float4 per (m,f))
// ---------------------------------------------------------------------------
__global__ void transpose_kernel(const float* __restrict__ x,
                                 float* __restrict__ T0, int MF) {
  int i = blockIdx.x * blockDim.x + threadIdx.x;
  if (i >= MF) return;
  float4 v;
  v.x = x[i];
  v.y = x[(size_t)MF + i];
  v.z = x[(size_t)2 * MF + i];
  v.w = x[(size_t)3 * MF + i];
  reinterpret_cast<float4*>(T0)[i] = v;
}

// ---------------------------------------------------------------------------
// 2. CSR build: histogram -> 3-kernel scan -> scatter (col+val fused int2)
// ---------------------------------------------------------------------------
__global__ void hist_kernel(const int* __restrict__ rows,
                            int* __restrict__ cursor, int E) {
  int e = blockIdx.x * blockDim.x + threadIdx.x;
  if (e < E) atomicAdd(&cursor[rows[e]], 1);
}

__global__ void scan1_kernel(const int* __restrict__ cnt,
                             int* __restrict__ bsum, int M) {
  int tid = threadIdx.x, lane = tid & 63, wid = tid >> 6;
  int i = blockIdx.x * 256 + tid;
  int v = (i < M) ? cnt[i] : 0;
#pragma unroll
  for (int off = 1; off < 64; off <<= 1) v += __shfl_xor(v, off);
  __shared__ int ws[4];
  if (lane == 0) ws[wid] = v;
  __syncthreads();
  if (tid == 0) bsum[blockIdx.x] = ws[0] + ws[1] + ws[2] + ws[3];
}

__global__ void scan2_kernel(int* __restrict__ bsum, int nb) {
  __shared__ int ws[8];
  __shared__ int tot;
  __shared__ int carry;
  int tid = threadIdx.x, lane = tid & 63, wid = tid >> 6;
  if (tid == 0) carry = 0;
  __syncthreads();
  for (int c0 = 0; c0 < nb; c0 += 512) {
    int i = c0 + tid;
    int v = (i < nb) ? bsum[i] : 0;
    int s = v;
#pragma unroll
    for (int off = 1; off < 64; off <<= 1) {
      int u = __shfl_up(s, off);
      if (lane >= off) s += u;
    }
    if (lane == 63) ws[wid] = s;
    __syncthreads();
    if (tid == 0) {
      int run = 0;
#pragma unroll
      for (int w = 0; w < 8; ++w) { int t = ws[w]; ws[w] = run; run += t; }
      tot = run;
    }
    __syncthreads();
    int excl = carry + ws[wid] + (s - v);
    if (i < nb) bsum[i] = excl;
    __syncthreads();
    if (tid == 0) carry += tot;
    __syncthreads();
  }
}

__global__ void scan3_kernel(const int* __restrict__ bsum,
                             int* __restrict__ row_start,
                             int* __restrict__ cursor, int M, int E) {
  __shared__ int wsum[4];
  int tid = threadIdx.x, lane = tid & 63, wid = tid >> 6;
  int i = blockIdx.x * 256 + tid;
  int v = (i < M) ? cursor[i] : 0;
  int s = v;
#pragma unroll
  for (int off = 1; off < 64; off <<= 1) {
    int u = __shfl_up(s, off);
    if (lane >= off) s += u;
  }
  if (lane == 63) wsum[wid] = s;
  __syncthreads();
  if (tid == 0) {
    int run = 0;
#pragma unroll
    for (int w = 0; w < 4; ++w) { int t = wsum[w]; wsum[w] = run; run += t; }
  }
  __syncthreads();
  int excl = bsum[blockIdx.x] + wsum[wid] + (s - v);
  if (i < M) { row_start[i] = excl; cursor[i] = excl; }
  if (i == 0) row_start[M] = E;
}

__global__ void scatter_kernel(const int* __restrict__ rows,
                               const int* __restrict__ cols,
                               const float* __restrict__ vals,
                               int* __restrict__ cursor,
                               int2* __restrict__ csr, int E) {
  int e = blockIdx.x * blockDim.x + threadIdx.x;
  if (e >= E) return;
  int r = rows[e];
  int p = atomicAdd(&cursor[r], 1);
  csr[p] = make_int2(cols[e], __float_as_int(vals[e]));
}

// ---------------------------------------------------------------------------
// 3. SpMM (wave per row, 16 gathers in flight via readlane broadcast):
//    dst[m,:] = alpha*Sum_e val*src[col,:] + beta*src[m,:] + gamma*prev[m,:]
// ---------------------------------------------------------------------------
__global__ __launch_bounds__(256) void spmm_kernel(
    const float* __restrict__ src, const float* __restrict__ prev,
    float* __restrict__ dst, const int* __restrict__ row_start,
    const int2* __restrict__ csr, int M,
    float alpha, float beta, float gamma) {
  int gw = (int)((blockIdx.x * (unsigned)blockDim.x + threadIdx.x) >> 6);
  int lane = threadIdx.x & 63;
  if (gw >= M) return;
  int s = row_start[gw];
  int e = row_start[gw + 1];
  const float2* src2 = reinterpret_cast<const float2*>(src);
  float ax = 0.f, ay = 0.f;
  int base = s;
  while (base < e) {
    int idx = base + (lane & 15);
    int2 cv = csr[idx < e ? idx : (e - 1)];   // one vector load per 16 edges
    int rem = e - base;
    if (rem >= 16) {
#pragma unroll
      for (int j = 0; j < 16; ++j) {
        int c = __builtin_amdgcn_readlane(cv.x, j);
        float v = __int_as_float(__builtin_amdgcn_readlane(cv.y, j));
        float2 a = src2[(size_t)c * 64 + lane];
        ax += v * a.x;
        ay += v * a.y;
      }
      base += 16;
    } else {
      for (int j = 0; j < rem; ++j) {
        int c = __builtin_amdgcn_readlane(cv.x, j);
        float v = __int_as_float(__builtin_amdgcn_readlane(cv.y, j));
        float2 a = src2[(size_t)c * 64 + lane];
        ax += v * a.x;
        ay += v * a.y;
      }
      base = e;
    }
  }
  float2 sv = src2[(size_t)gw * 64 + lane];
  ax = alpha * ax + beta * sv.x;
  ay = alpha * ay + beta * sv.y;
  if (prev) {
    float2 pv = reinterpret_cast<const float2*>(prev)[(size_t)gw * 64 + lane];
    ax += gamma * pv.x;
    ay += gamma * pv.y;
  }
  float2 o; o.x = ax; o.y = ay;
  reinterpret_cast<float2*>(dst)[(size_t)gw * 64 + lane] = o;
}

// ---------------------------------------------------------------------------
// 4. Final GEMM: out[n*M+m, fo] = Sum_{f,k} Tk[m, f*4+n] * W[f*4+k, fo]
//    LDS X tile [r=128][rho=64 (+4 pad)]: rho = mv*4+n, r = f*4+k.
//    Stage: float4 global read (64B segments) -> float4 LDS write.
//    Compute: per thread 1x ds_read_b128 (4 rows, free 2-way banks) +
//    1x global float4 W (L1 broadcast) + 16 FMA per r.
// ---------------------------------------------------------------------------
__global__ __launch_bounds__(256) void gemm_kernel(
    const float* __restrict__ Tbase, const float* __restrict__ W,
    float* __restrict__ out, int M) {
  __shared__ float Xl[128 * 68];
  int tid = threadIdx.x;
  int m0 = blockIdx.x * 16;
  size_t M32 = (size_t)M * 32;  // float4s per T buffer row-block
  const float4* T4 = reinterpret_cast<const float4*>(Tbase);
#pragma unroll
  for (int t = 0; t < 8; ++t) {
    int i = tid + t * 256;
    int mv = i & 15;          // inner: lanes spread over mv -> LDS banks spread
    int cq = (i >> 4) & 31;   // float4 column quad (f = cq)
    int k = (i >> 9) & 3;
    int m = m0 + mv;
    float4 g = make_float4(0.f, 0.f, 0.f, 0.f);
    if (m < M) g = T4[(size_t)k * M32 + (size_t)m * 32 + cq];
    int r = cq * 4 + k;
    *reinterpret_cast<float4*>(&Xl[r * 68 + mv * 4]) = g;
  }
  __syncthreads();

  int rg = tid & 15;        // vertex within tile; rows rho = 4*rg+n
  int fg = tid >> 4;        // fo quad: fo0 = 4*fg
  const float4* W4 = reinterpret_cast<const float4*>(W);
  float4 a0 = make_float4(0.f, 0.f, 0.f, 0.f);
  float4 a1 = a0, a2 = a0, a3 = a0;
#pragma unroll 4
  for (int r = 0; r < 128; ++r) {
    float4 xv = *reinterpret_cast<const float4*>(&Xl[r * 68 + rg * 4]);
    float4 wv = W4[r * 16 + fg];
    a0.x += xv.x * wv.x; a0.y += xv.x * wv.y; a0.z += xv.x * wv.z; a0.w += xv.x * wv.w;
    a1.x += xv.y * wv.x; a1.y += xv.y * wv.y; a1.z += xv.y * wv.z; a1.w += xv.y * wv.w;
    a2.x += xv.z * wv.x; a2.y += xv.z * wv.y; a2.z += xv.z * wv.z; a2.w += xv.z * wv.w;
    a3.x += xv.w * wv.x; a3.y += xv.w * wv.y; a3.z += xv.w * wv.z; a3.w += xv.w * wv.w;
  }
  int m = m0 + rg;
  if (m < M) {
    int fo0 = fg * 4;
    *reinterpret_cast<float4*>(&out[((size_t)0 * M + m) * FOUT + fo0]) = a0;
    *reinterpret_cast<float4*>(&out[((size_t)1 * M + m) * FOUT + fo0]) = a1;
    *reinterpret_cast<float4*>(&out[((size_t)2 * M + m) * FOUT + fo0]) = a2;
    *reinterpret_cast<float4*>(&out[((size_t)3 * M + m) * FOUT + fo0]) = a3;
  }
}

// ---------------------------------------------------------------------------
extern "C" void kernel_launch(void* const* d_in, const int* in_sizes, int n_in,
                              void* d_out, int out_size, void* d_ws, size_t ws_size,
                              hipStream_t stream) {
  const float* x         = (const float*)d_in[0];
  const float* edge_vals = (const float*)d_in[1];
  const float* W         = (const float*)d_in[2];
  const int* edge_rows   = (const int*)d_in[3];
  const int* edge_cols   = (const int*)d_in[4];
  float* out = (float*)d_out;

  int M = in_sizes[0] / (N_DIM * FIN);
  int E = in_sizes[1];
  int MF = M * FIN;
  int nb = (M + 255) / 256;

  char* ws = (char*)d_ws;
  size_t tsz = (size_t)M * ROWLEN * sizeof(float);
  float* Tbase = (float*)ws;
  int2* csr = (int2*)(ws + 4 * tsz);                 // 8B aligned (4*tsz % 8 == 0)
  int* row_start = (int*)((char*)csr + (size_t)E * sizeof(int2));
  int* cursor = row_start + (M + 1);
  int* bsum = cursor + M;

  float* T0 = Tbase;
  float* T1 = T0 + (size_t)M * ROWLEN;
  float* T2 = T1 + (size_t)M * ROWLEN;
  float* T3 = T2 + (size_t)M * ROWLEN;

  hipMemsetAsync(cursor, 0, (size_t)M * sizeof(int), stream);

  transpose_kernel<<<(MF + 255) / 256, 256, 0, stream>>>(x, T0, MF);
  hist_kernel<<<(E + 255) / 256, 256, 0, stream>>>(edge_rows, cursor, E);
  scan1_kernel<<<nb, 256, 0, stream>>>(cursor, bsum, M);
  scan2_kernel<<<1, 512, 0, stream>>>(bsum, nb);
  scan3_kernel<<<nb, 256, 0, stream>>>(bsum, row_start, cursor, M, E);
  scatter_kernel<<<(E + 255) / 256, 256, 0, stream>>>(edge_rows, edge_cols, edge_vals,
                                                      cursor, csr, E);

  int spmm_blocks = (M + 3) / 4;  // wave per row, 4 waves/block
  spmm_kernel<<<spmm_blocks, 256, 0, stream>>>(T0, nullptr, T1, row_start, csr,
                                               M, 1.f, -1.f, 0.f);
  spmm_kernel<<<spmm_blocks, 256, 0, stream>>>(T1, T0, T2, row_start, csr,
                                               M, 2.f, -2.f, -1.f);
  spmm_kernel<<<spmm_blocks, 256, 0, stream>>>(T2, T1, T3, row_start, csr,
                                               M, 2.f, -2.f, -1.f);

  gemm_kernel<<<(M + 15) / 16, 256, 0, stream>>>(Tbase, W, out, M);
}

// Round 3
// 730.751 us; speedup vs baseline: 1.3490x; 1.0312x over previous
//
#include <hip/hip_runtime.h>
#include <hip/hip_bf16.h>
#include <stdint.h>

#define N_DIM 4
#define FIN 32
#define KORD 4
#define FOUT 64
#define ROWLEN 128   // FIN * N_DIM

// ---------------------------------------------------------------------------
// 1. Transpose x[N][M][Fin] -> T0[m][f*4+n]  (float4 per (m,f))
// ---------------------------------------------------------------------------
__global__ void transpose_kernel(const float* __restrict__ x,
                                 float* __restrict__ T0, int MF) {
  int i = blockIdx.x * blockDim.x + threadIdx.x;
  if (i >= MF) return;
  float4 v;
  v.x = x[i];
  v.y = x[(size_t)MF + i];
  v.z = x[(size_t)2 * MF + i];
  v.w = x[(size_t)3 * MF + i];
  reinterpret_cast<float4*>(T0)[i] = v;
}

// ---------------------------------------------------------------------------
// 2. CSR build: histogram -> 3-kernel scan -> scatter (col+val fused int2)
// ---------------------------------------------------------------------------
__global__ void hist_kernel(const int* __restrict__ rows,
                            int* __restrict__ cursor, int E) {
  int e = blockIdx.x * blockDim.x + threadIdx.x;
  if (e < E) atomicAdd(&cursor[rows[e]], 1);
}

__global__ void scan1_kernel(const int* __restrict__ cnt,
                             int* __restrict__ bsum, int M) {
  int tid = threadIdx.x, lane = tid & 63, wid = tid >> 6;
  int i = blockIdx.x * 256 + tid;
  int v = (i < M) ? cnt[i] : 0;
#pragma unroll
  for (int off = 1; off < 64; off <<= 1) v += __shfl_xor(v, off);
  __shared__ int ws[4];
  if (lane == 0) ws[wid] = v;
  __syncthreads();
  if (tid == 0) bsum[blockIdx.x] = ws[0] + ws[1] + ws[2] + ws[3];
}

__global__ void scan2_kernel(int* __restrict__ bsum, int nb) {
  __shared__ int ws[8];
  __shared__ int tot;
  __shared__ int carry;
  int tid = threadIdx.x, lane = tid & 63, wid = tid >> 6;
  if (tid == 0) carry = 0;
  __syncthreads();
  for (int c0 = 0; c0 < nb; c0 += 512) {
    int i = c0 + tid;
    int v = (i < nb) ? bsum[i] : 0;
    int s = v;
#pragma unroll
    for (int off = 1; off < 64; off <<= 1) {
      int u = __shfl_up(s, off);
      if (lane >= off) s += u;
    }
    if (lane == 63) ws[wid] = s;
    __syncthreads();
    if (tid == 0) {
      int run = 0;
#pragma unroll
      for (int w = 0; w < 8; ++w) { int t = ws[w]; ws[w] = run; run += t; }
      tot = run;
    }
    __syncthreads();
    int excl = carry + ws[wid] + (s - v);
    if (i < nb) bsum[i] = excl;
    __syncthreads();
    if (tid == 0) carry += tot;
    __syncthreads();
  }
}

__global__ void scan3_kernel(const int* __restrict__ bsum,
                             int* __restrict__ row_start,
                             int* __restrict__ cursor, int M, int E) {
  __shared__ int wsum[4];
  int tid = threadIdx.x, lane = tid & 63, wid = tid >> 6;
  int i = blockIdx.x * 256 + tid;
  int v = (i < M) ? cursor[i] : 0;
  int s = v;
#pragma unroll
  for (int off = 1; off < 64; off <<= 1) {
    int u = __shfl_up(s, off);
    if (lane >= off) s += u;
  }
  if (lane == 63) wsum[wid] = s;
  __syncthreads();
  if (tid == 0) {
    int run = 0;
#pragma unroll
    for (int w = 0; w < 4; ++w) { int t = wsum[w]; wsum[w] = run; run += t; }
  }
  __syncthreads();
  int excl = bsum[blockIdx.x] + wsum[wid] + (s - v);
  if (i < M) { row_start[i] = excl; cursor[i] = excl; }
  if (i == 0) row_start[M] = E;
}

__global__ void scatter_kernel(const int* __restrict__ rows,
                               const int* __restrict__ cols,
                               const float* __restrict__ vals,
                               int* __restrict__ cursor,
                               int2* __restrict__ csr, int E) {
  int e = blockIdx.x * blockDim.x + threadIdx.x;
  if (e >= E) return;
  int r = rows[e];
  int p = atomicAdd(&cursor[r], 1);
  csr[p] = make_int2(cols[e], __float_as_int(vals[e]));
}

// ---------------------------------------------------------------------------
// 3. SpMM (wave per row; edge list read on the SCALAR pipe):
//    dst[m,:] = alpha*Sum_e val*src[col,:] + beta*src[m,:] + gamma*prev[m,:]
//    gw/s/e/csr[j] are wave-uniform -> s_load; per edge: 1 VMEM gather +
//    2 v_fmac (edge weight rides the SGPR operand). 8 gathers in flight.
// ---------------------------------------------------------------------------
__global__ __launch_bounds__(256) void spmm_kernel(
    const float* __restrict__ src, const float* __restrict__ prev,
    float* __restrict__ dst, const int* __restrict__ row_start,
    const int2* __restrict__ csr, int M,
    float alpha, float beta, float gamma) {
  int wid = __builtin_amdgcn_readfirstlane((int)threadIdx.x >> 6);
  int gw = blockIdx.x * 4 + wid;
  int lane = threadIdx.x & 63;
  if (gw >= M) return;
  int s = row_start[gw];
  int e = row_start[gw + 1];
  const float2* src2 = reinterpret_cast<const float2*>(src);
  float ax = 0.f, ay = 0.f;
  int j = s;
  for (; j + 8 <= e; j += 8) {
#pragma unroll
    for (int u = 0; u < 8; ++u) {
      int2 cv = csr[j + u];                       // uniform -> s_load
      float2 a = src2[(size_t)(unsigned)cv.x * 64 + lane];
      float v = __int_as_float(cv.y);
      ax += v * a.x;
      ay += v * a.y;
    }
  }
  for (; j < e; ++j) {
    int2 cv = csr[j];
    float2 a = src2[(size_t)(unsigned)cv.x * 64 + lane];
    float v = __int_as_float(cv.y);
    ax += v * a.x;
    ay += v * a.y;
  }
  float2 sv = src2[(size_t)gw * 64 + lane];
  ax = alpha * ax + beta * sv.x;
  ay = alpha * ay + beta * sv.y;
  if (prev) {
    float2 pv = reinterpret_cast<const float2*>(prev)[(size_t)gw * 64 + lane];
    ax += gamma * pv.x;
    ay += gamma * pv.y;
  }
  float2 o; o.x = ax; o.y = ay;
  reinterpret_cast<float2*>(dst)[(size_t)gw * 64 + lane] = o;
}

// ---------------------------------------------------------------------------
// 4. Final GEMM: out[n*M+m, fo] = Sum_{f,k} Tk[m, f*4+n] * W[f*4+k, fo]
//    X tile in LDS as [r=128][rho=64]; lane reads Xl[r*64+lane] (b32,
//    2 lanes/bank = free). Wave w owns fo quad-group [16w,16w+16): W loads
//    are wave-uniform -> s_load from K$ (off the VMEM+VALU pipes).
//    Inner loop per r: 1 ds_read_b32 + 16 v_fmac (SGPR weight operand).
// ---------------------------------------------------------------------------
__global__ __launch_bounds__(256) void gemm_kernel(
    const float* __restrict__ Tbase, const float* __restrict__ W,
    float* __restrict__ out, int M) {
  __shared__ float Xl[128 * 64];
  int tid = threadIdx.x;
  int m0 = blockIdx.x * 16;
  size_t M32 = (size_t)M * 32;  // float4s per T buffer
  const float4* T4 = reinterpret_cast<const float4*>(Tbase);
#pragma unroll
  for (int t = 0; t < 8; ++t) {
    int i = tid + t * 256;
    int mv = i & 15;          // vertex within tile (inner -> line-coalesced)
    int f  = (i >> 4) & 31;   // feature quad
    int k  = (i >> 9) & 3;    // Chebyshev order
    int m = m0 + mv;
    float4 g = make_float4(0.f, 0.f, 0.f, 0.f);
    if (m < M) g = T4[(size_t)k * M32 + (size_t)m * 32 + f];
    int r = f * 4 + k;        // W row index
    *reinterpret_cast<float4*>(&Xl[r * 64 + mv * 4]) = g;  // rho = 4*mv+n
  }
  __syncthreads();

  int lane = tid & 63;
  int fo0 = __builtin_amdgcn_readfirstlane(((int)tid >> 6) << 4);
  const float* Wp = W + fo0;
  float acc[16];
#pragma unroll
  for (int q = 0; q < 16; ++q) acc[q] = 0.f;
#pragma unroll 4
  for (int r = 0; r < 128; ++r) {
    float xv = Xl[r * 64 + lane];
#pragma unroll
    for (int q = 0; q < 16; ++q)
      acc[q] += xv * Wp[r * FOUT + q];   // uniform -> s_load (K$)
  }

  int m = m0 + (lane >> 2);
  int n = lane & 3;
  if (m < M) {
    float4* o = reinterpret_cast<float4*>(&out[((size_t)n * M + m) * FOUT + fo0]);
    o[0] = make_float4(acc[0], acc[1], acc[2], acc[3]);
    o[1] = make_float4(acc[4], acc[5], acc[6], acc[7]);
    o[2] = make_float4(acc[8], acc[9], acc[10], acc[11]);
    o[3] = make_float4(acc[12], acc[13], acc[14], acc[15]);
  }
}

// ---------------------------------------------------------------------------
extern "C" void kernel_launch(void* const* d_in, const int* in_sizes, int n_in,
                              void* d_out, int out_size, void* d_ws, size_t ws_size,
                              hipStream_t stream) {
  const float* x         = (const float*)d_in[0];
  const float* edge_vals = (const float*)d_in[1];
  const float* W         = (const float*)d_in[2];
  const int* edge_rows   = (const int*)d_in[3];
  const int* edge_cols   = (const int*)d_in[4];
  float* out = (float*)d_out;

  int M = in_sizes[0] / (N_DIM * FIN);
  int E = in_sizes[1];
  int MF = M * FIN;
  int nb = (M + 255) / 256;

  char* ws = (char*)d_ws;
  size_t tsz = (size_t)M * ROWLEN * sizeof(float);
  float* Tbase = (float*)ws;
  int2* csr = (int2*)(ws + 4 * tsz);
  int* row_start = (int*)((char*)csr + (size_t)E * sizeof(int2));
  int* cursor = row_start + (M + 1);
  int* bsum = cursor + M;

  float* T0 = Tbase;
  float* T1 = T0 + (size_t)M * ROWLEN;
  float* T2 = T1 + (size_t)M * ROWLEN;
  float* T3 = T2 + (size_t)M * ROWLEN;

  hipMemsetAsync(cursor, 0, (size_t)M * sizeof(int), stream);

  transpose_kernel<<<(MF + 255) / 256, 256, 0, stream>>>(x, T0, MF);
  hist_kernel<<<(E + 255) / 256, 256, 0, stream>>>(edge_rows, cursor, E);
  scan1_kernel<<<nb, 256, 0, stream>>>(cursor, bsum, M);
  scan2_kernel<<<1, 512, 0, stream>>>(bsum, nb);
  scan3_kernel<<<nb, 256, 0, stream>>>(bsum, row_start, cursor, M, E);
  scatter_kernel<<<(E + 255) / 256, 256, 0, stream>>>(edge_rows, edge_cols, edge_vals,
                                                      cursor, csr, E);

  int spmm_blocks = (M + 3) / 4;  // wave per row, 4 waves/block
  spmm_kernel<<<spmm_blocks, 256, 0, stream>>>(T0, nullptr, T1, row_start, csr,
                                               M, 1.f, -1.f, 0.f);
  spmm_kernel<<<spmm_blocks, 256, 0, stream>>>(T1, T0, T2, row_start, csr,
                                               M, 2.f, -2.f, -1.f);
  spmm_kernel<<<spmm_blocks, 256, 0, stream>>>(T2, T1, T3, row_start, csr,
                                               M, 2.f, -2.f, -1.f);

  gemm_kernel<<<(M + 15) / 16, 256, 0, stream>>>(Tbase, W, out, M);
}

// Round 4
// 493.682 us; speedup vs baseline: 1.9967x; 1.4802x over previous
//
#include <hip/hip_runtime.h>
#include <hip/hip_bf16.h>
#include <stdint.h>

#define N_DIM 4
#define FIN 32
#define KORD 4
#define FOUT 64
#define ROWLEN 128   // FIN * N_DIM

typedef __attribute__((ext_vector_type(4))) float f32x4;
typedef __attribute__((ext_vector_type(8))) short bf16x8;

__device__ __forceinline__ ushort f32_to_bf16_rn(float f) {
  uint u = __float_as_uint(f);
  u += 0x7FFFu + ((u >> 16) & 1u);     // round-to-nearest-even
  return (ushort)(u >> 16);
}
__device__ __forceinline__ float bf16_lo(uint p) { return __uint_as_float(p << 16); }
__device__ __forceinline__ float bf16_hi(uint p) { return __uint_as_float(p & 0xFFFF0000u); }

// ---------------------------------------------------------------------------
// 1. Transpose x[N][M][Fin] -> T0f[m][f*4+n] fp32 + Tb0 bf16 copy
// ---------------------------------------------------------------------------
__global__ void transpose_kernel(const float* __restrict__ x,
                                 float* __restrict__ T0,
                                 ushort* __restrict__ Tb0, int MF) {
  int i = blockIdx.x * blockDim.x + threadIdx.x;
  if (i >= MF) return;
  float4 v;
  v.x = x[i];
  v.y = x[(size_t)MF + i];
  v.z = x[(size_t)2 * MF + i];
  v.w = x[(size_t)3 * MF + i];
  reinterpret_cast<float4*>(T0)[i] = v;
  ushort4 h;
  h.x = f32_to_bf16_rn(v.x);
  h.y = f32_to_bf16_rn(v.y);
  h.z = f32_to_bf16_rn(v.z);
  h.w = f32_to_bf16_rn(v.w);
  reinterpret_cast<ushort4*>(Tb0)[i] = h;
}

// ---------------------------------------------------------------------------
// 2. CSR build: histogram -> 3-kernel scan -> scatter (col+val fused int2)
// ---------------------------------------------------------------------------
__global__ void hist_kernel(const int* __restrict__ rows,
                            int* __restrict__ cursor, int E) {
  int e = blockIdx.x * blockDim.x + threadIdx.x;
  if (e < E) atomicAdd(&cursor[rows[e]], 1);
}

__global__ void scan1_kernel(const int* __restrict__ cnt,
                             int* __restrict__ bsum, int M) {
  int tid = threadIdx.x, lane = tid & 63, wid = tid >> 6;
  int i = blockIdx.x * 256 + tid;
  int v = (i < M) ? cnt[i] : 0;
#pragma unroll
  for (int off = 1; off < 64; off <<= 1) v += __shfl_xor(v, off);
  __shared__ int ws[4];
  if (lane == 0) ws[wid] = v;
  __syncthreads();
  if (tid == 0) bsum[blockIdx.x] = ws[0] + ws[1] + ws[2] + ws[3];
}

__global__ void scan2_kernel(int* __restrict__ bsum, int nb) {
  __shared__ int ws[8];
  __shared__ int tot;
  __shared__ int carry;
  int tid = threadIdx.x, lane = tid & 63, wid = tid >> 6;
  if (tid == 0) carry = 0;
  __syncthreads();
  for (int c0 = 0; c0 < nb; c0 += 512) {
    int i = c0 + tid;
    int v = (i < nb) ? bsum[i] : 0;
    int s = v;
#pragma unroll
    for (int off = 1; off < 64; off <<= 1) {
      int u = __shfl_up(s, off);
      if (lane >= off) s += u;
    }
    if (lane == 63) ws[wid] = s;
    __syncthreads();
    if (tid == 0) {
      int run = 0;
#pragma unroll
      for (int w = 0; w < 8; ++w) { int t = ws[w]; ws[w] = run; run += t; }
      tot = run;
    }
    __syncthreads();
    int excl = carry + ws[wid] + (s - v);
    if (i < nb) bsum[i] = excl;
    __syncthreads();
    if (tid == 0) carry += tot;
    __syncthreads();
  }
}

__global__ void scan3_kernel(const int* __restrict__ bsum,
                             int* __restrict__ row_start,
                             int* __restrict__ cursor, int M, int E) {
  __shared__ int wsum[4];
  int tid = threadIdx.x, lane = tid & 63, wid = tid >> 6;
  int i = blockIdx.x * 256 + tid;
  int v = (i < M) ? cursor[i] : 0;
  int s = v;
#pragma unroll
  for (int off = 1; off < 64; off <<= 1) {
    int u = __shfl_up(s, off);
    if (lane >= off) s += u;
  }
  if (lane == 63) wsum[wid] = s;
  __syncthreads();
  if (tid == 0) {
    int run = 0;
#pragma unroll
    for (int w = 0; w < 4; ++w) { int t = wsum[w]; wsum[w] = run; run += t; }
  }
  __syncthreads();
  int excl = bsum[blockIdx.x] + wsum[wid] + (s - v);
  if (i < M) { row_start[i] = excl; cursor[i] = excl; }
  if (i == 0) row_start[M] = E;
}

__global__ void scatter_kernel(const int* __restrict__ rows,
                               const int* __restrict__ cols,
                               const float* __restrict__ vals,
                               int* __restrict__ cursor,
                               int2* __restrict__ csr, int E) {
  int e = blockIdx.x * blockDim.x + threadIdx.x;
  if (e >= E) return;
  int r = rows[e];
  int p = atomicAdd(&cursor[r], 1);
  csr[p] = make_int2(cols[e], __float_as_int(vals[e]));
}

// ---------------------------------------------------------------------------
// 3. SpMM (wave per row; scalar-pipe edges; bf16 gather, fp32 self term):
//    dst = alpha*Sum val*srcb[col] + beta*srcf[m] + gamma*prevb[m]
//    Writes fp32 (optional) + bf16 copy.
// ---------------------------------------------------------------------------
__global__ __launch_bounds__(256) void spmm_kernel(
    const float* __restrict__ srcf, const uint* __restrict__ srcb,
    const uint* __restrict__ prevb,
    float* __restrict__ dstf, uint* __restrict__ dstb,
    const int* __restrict__ row_start, const int2* __restrict__ csr,
    int M, float alpha, float beta, float gamma, int write_f32) {
  int wid = __builtin_amdgcn_readfirstlane((int)threadIdx.x >> 6);
  int gw = blockIdx.x * 4 + wid;
  int lane = threadIdx.x & 63;
  if (gw >= M) return;
  int s = row_start[gw];
  int e = row_start[gw + 1];
  float ax = 0.f, ay = 0.f;
  int j = s;
  for (; j + 8 <= e; j += 8) {
#pragma unroll
    for (int u = 0; u < 8; ++u) {
      int2 cv = csr[j + u];                              // uniform -> s_load
      uint p = srcb[(size_t)(unsigned)cv.x * 64 + lane]; // 256B row gather
      float v = __int_as_float(cv.y);
      ax += v * bf16_lo(p);
      ay += v * bf16_hi(p);
    }
  }
  for (; j < e; ++j) {
    int2 cv = csr[j];
    uint p = srcb[(size_t)(unsigned)cv.x * 64 + lane];
    float v = __int_as_float(cv.y);
    ax += v * bf16_lo(p);
    ay += v * bf16_hi(p);
  }
  float2 sv = reinterpret_cast<const float2*>(srcf)[(size_t)gw * 64 + lane];
  ax = alpha * ax + beta * sv.x;
  ay = alpha * ay + beta * sv.y;
  if (prevb) {
    uint pp = prevb[(size_t)gw * 64 + lane];
    ax += gamma * bf16_lo(pp);
    ay += gamma * bf16_hi(pp);
  }
  if (write_f32)
    reinterpret_cast<float2*>(dstf)[(size_t)gw * 64 + lane] = make_float2(ax, ay);
  dstb[(size_t)gw * 64 + lane] =
      (uint)f32_to_bf16_rn(ax) | ((uint)f32_to_bf16_rn(ay) << 16);
}

// ---------------------------------------------------------------------------
// 4. Final GEMM via MFMA 16x16x32 bf16, no LDS.
//    XS[row=m*4+n][c=f*4+k] = Tb_k[m][f*4+n]; out[n*M+m] = XS row @ W.
//    One wave per 16-row tile (4 vertices), grid-stride; B-frags (W, bf16 RN)
//    hoisted once per wave; A-frags gathered as 8 ushorts/lane.
// ---------------------------------------------------------------------------
__global__ __launch_bounds__(256) void gemm_kernel(
    const ushort* __restrict__ Tb0, const ushort* __restrict__ Tb1,
    const ushort* __restrict__ Tb2, const ushort* __restrict__ Tb3,
    const float* __restrict__ W, float* __restrict__ out,
    int M, int nwaves) {
  int lane = threadIdx.x & 63;
  int gwave = blockIdx.x * 4 + ((int)threadIdx.x >> 6);
  int g = lane >> 4;   // 0..3 (k-chunk group / store vertex)
  int q = lane & 15;   // A row within tile / output column within fo-tile

  // B fragments: b[t][ft][e] = W[t*32 + g*8 + e][ft*16 + q]  (bf16 RN)
  bf16x8 b[4][4];
#pragma unroll
  for (int t = 0; t < 4; ++t) {
#pragma unroll
    for (int ft = 0; ft < 4; ++ft) {
#pragma unroll
      for (int e = 0; e < 8; ++e) {
        float w = W[(t * 32 + g * 8 + e) * FOUT + ft * 16 + q];
        b[t][ft][e] = (short)f32_to_bf16_rn(w);
      }
    }
  }

  int NT = (M + 3) >> 2;
  for (int tile = gwave; tile < NT; tile += nwaves) {
    int m0 = tile * 4;
    int mA = m0 + (q >> 2);          // A-fragment vertex for this lane
    if (mA > M - 1) mA = M - 1;      // clamp (garbage rows are store-guarded)
    int n = q & 3;
    size_t abase = (size_t)mA * ROWLEN + n;

    f32x4 C0 = {0.f, 0.f, 0.f, 0.f};
    f32x4 C1 = C0, C2 = C0, C3 = C0;
#pragma unroll
    for (int t = 0; t < 4; ++t) {
      int kc = t * 4 + g;
      bf16x8 a;
#pragma unroll
      for (int e = 0; e < 8; ++e) {
        int colT = (2 * kc + (e >> 2)) * 4;   // T column = (f)*4, +n in abase
        const ushort* Tb = (e & 3) == 0 ? Tb0 : (e & 3) == 1 ? Tb1
                         : (e & 3) == 2 ? Tb2 : Tb3;
        a[e] = (short)Tb[abase + colT];
      }
      C0 = __builtin_amdgcn_mfma_f32_16x16x32_bf16(a, b[t][0], C0, 0, 0, 0);
      C1 = __builtin_amdgcn_mfma_f32_16x16x32_bf16(a, b[t][1], C1, 0, 0, 0);
      C2 = __builtin_amdgcn_mfma_f32_16x16x32_bf16(a, b[t][2], C2, 0, 0, 0);
      C3 = __builtin_amdgcn_mfma_f32_16x16x32_bf16(a, b[t][3], C3, 0, 0, 0);
    }
    // C mapping: col = q, row = g*4 + r  ->  vertex m0+g, n = r
    int mS = m0 + g;
    if (mS < M) {
#pragma unroll
      for (int r = 0; r < 4; ++r) {
        size_t ob = ((size_t)r * M + mS) * FOUT + q;
        out[ob +  0] = C0[r];
        out[ob + 16] = C1[r];
        out[ob + 32] = C2[r];
        out[ob + 48] = C3[r];
      }
    }
  }
}

// ---------------------------------------------------------------------------
extern "C" void kernel_launch(void* const* d_in, const int* in_sizes, int n_in,
                              void* d_out, int out_size, void* d_ws, size_t ws_size,
                              hipStream_t stream) {
  const float* x         = (const float*)d_in[0];
  const float* edge_vals = (const float*)d_in[1];
  const float* W         = (const float*)d_in[2];
  const int* edge_rows   = (const int*)d_in[3];
  const int* edge_cols   = (const int*)d_in[4];
  float* out = (float*)d_out;

  int M = in_sizes[0] / (N_DIM * FIN);
  int E = in_sizes[1];
  int MF = M * FIN;
  int nb = (M + 255) / 256;

  char* ws = (char*)d_ws;
  size_t rowf = (size_t)M * ROWLEN;           // floats per fp32 T buffer
  float* Tf0 = (float*)ws;
  float* Tf1 = Tf0 + rowf;
  int2* csr = (int2*)(ws + 2 * rowf * sizeof(float));
  ushort* Tb0 = (ushort*)((char*)csr + (size_t)E * sizeof(int2));
  ushort* Tb1 = Tb0 + rowf;
  ushort* Tb2 = Tb1 + rowf;
  ushort* Tb3 = Tb2 + rowf;
  int* row_start = (int*)(Tb3 + rowf);
  int* cursor = row_start + (M + 1);
  int* bsum = cursor + M;

  hipMemsetAsync(cursor, 0, (size_t)M * sizeof(int), stream);

  transpose_kernel<<<(MF + 255) / 256, 256, 0, stream>>>(x, Tf0, Tb0, MF);
  hist_kernel<<<(E + 255) / 256, 256, 0, stream>>>(edge_rows, cursor, E);
  scan1_kernel<<<nb, 256, 0, stream>>>(cursor, bsum, M);
  scan2_kernel<<<1, 512, 0, stream>>>(bsum, nb);
  scan3_kernel<<<nb, 256, 0, stream>>>(bsum, row_start, cursor, M, E);
  scatter_kernel<<<(E + 255) / 256, 256, 0, stream>>>(edge_rows, edge_cols, edge_vals,
                                                      cursor, csr, E);

  int spmm_blocks = (M + 3) / 4;  // wave per row, 4 waves/block
  // T1 = L'T0:   1*gather(Tb0) - 1*Tf0
  spmm_kernel<<<spmm_blocks, 256, 0, stream>>>(
      Tf0, (const uint*)Tb0, nullptr, Tf1, (uint*)Tb1, row_start, csr,
      M, 1.f, -1.f, 0.f, 1);
  // T2 = 2L'T1 - T0: 2*gather(Tb1) - 2*Tf1 - 1*Tb0   (dst fp32 -> Tf0 reuse)
  spmm_kernel<<<spmm_blocks, 256, 0, stream>>>(
      Tf1, (const uint*)Tb1, (const uint*)Tb0, Tf0, (uint*)Tb2, row_start, csr,
      M, 2.f, -2.f, -1.f, 1);
  // T3 = 2L'T2 - T1: fp32 output not needed
  spmm_kernel<<<spmm_blocks, 256, 0, stream>>>(
      Tf0, (const uint*)Tb2, (const uint*)Tb1, Tf1, (uint*)Tb3, row_start, csr,
      M, 2.f, -2.f, -1.f, 0);

  int gemm_blocks = 1024;  // 4096 waves, grid-stride over (M+3)/4 tiles
  gemm_kernel<<<gemm_blocks, 256, 0, stream>>>(
      Tb0, Tb1, Tb2, Tb3, W, out, M, gemm_blocks * 4);
}

// Round 5
// 350.886 us; speedup vs baseline: 2.8093x; 1.4070x over previous
//
#include <hip/hip_runtime.h>
#include <hip/hip_bf16.h>
#include <stdint.h>

#define N_DIM 4
#define FIN 32
#define FOUT 64
#define ROWLEN 128   // FIN * N_DIM
#define NBLK 256     // edge chunks for the counting sort
#define BMAX 512     // max buckets (rows/256), M <= 131072

typedef __attribute__((ext_vector_type(4))) float f32x4;
typedef __attribute__((ext_vector_type(8))) short bf16x8;

__device__ __forceinline__ ushort f32_to_bf16_rn(float f) {
  uint u = __float_as_uint(f);
  u += 0x7FFFu + ((u >> 16) & 1u);     // round-to-nearest-even
  return (ushort)(u >> 16);
}
__device__ __forceinline__ float bf16_lo(uint p) { return __uint_as_float(p << 16); }
__device__ __forceinline__ float bf16_hi(uint p) { return __uint_as_float(p & 0xFFFF0000u); }

// ---------------------------------------------------------------------------
// 1. Transpose x[N][M][Fin] -> Tf[m][f*4+n] fp32 + Tb0 bf16 copy
// ---------------------------------------------------------------------------
__global__ void transpose_kernel(const float* __restrict__ x,
                                 float* __restrict__ Tf,
                                 ushort* __restrict__ Tb0, int MF) {
  int i = blockIdx.x * blockDim.x + threadIdx.x;
  if (i >= MF) return;
  float4 v;
  v.x = x[i];
  v.y = x[(size_t)MF + i];
  v.z = x[(size_t)2 * MF + i];
  v.w = x[(size_t)3 * MF + i];
  reinterpret_cast<float4*>(Tf)[i] = v;
  ushort4 h;
  h.x = f32_to_bf16_rn(v.x);
  h.y = f32_to_bf16_rn(v.y);
  h.z = f32_to_bf16_rn(v.z);
  h.w = f32_to_bf16_rn(v.w);
  reinterpret_cast<ushort4*>(Tb0)[i] = h;
}

// ---------------------------------------------------------------------------
// 2. CSR build — two-level counting sort with block-private regions.
//    bucket = row >> 8 (256 rows); entry packed as (col | rowlow<<17, val).
// ---------------------------------------------------------------------------
__global__ __launch_bounds__(256) void bcount_kernel(
    const int* __restrict__ rows, int* __restrict__ c, int E, int B, int ce) {
  __shared__ int hist[BMAX];
  int tid = threadIdx.x, blk = blockIdx.x;
  for (int b = tid; b < B; b += 256) hist[b] = 0;
  __syncthreads();
  int start = blk * ce;
  int end = min(E, start + ce);
  for (int e = start + tid; e < end; e += 256)
    atomicAdd(&hist[rows[e] >> 8], 1);
  __syncthreads();
  for (int b = tid; b < B; b += 256) c[b * NBLK + blk] = hist[b];
}

// per-bucket exclusive scan over the 256 block counts (in place) + totals
__global__ __launch_bounds__(256) void bscanA_kernel(
    int* __restrict__ c, int* __restrict__ btot) {
  __shared__ int wsum[4];
  int b = blockIdx.x, tid = threadIdx.x;
  int lane = tid & 63, wid = tid >> 6;
  int v = c[b * NBLK + tid];
  int s = v;
#pragma unroll
  for (int off = 1; off < 64; off <<= 1) {
    int u = __shfl_up(s, off);
    if (lane >= off) s += u;
  }
  if (lane == 63) wsum[wid] = s;
  __syncthreads();
  if (tid == 0) {
    int run = 0;
#pragma unroll
    for (int w = 0; w < 4; ++w) { int t = wsum[w]; wsum[w] = run; run += t; }
  }
  __syncthreads();
  int excl = wsum[wid] + s - v;
  c[b * NBLK + tid] = excl;
  if (tid == 255) btot[b] = excl + v;
}

// scan bucket totals -> bucket_start (B <= 512, one 512-thread block)
__global__ __launch_bounds__(512) void bscanB_kernel(
    const int* __restrict__ btot, int* __restrict__ bucket_start,
    int* __restrict__ row_start, int B, int M, int E) {
  __shared__ int wsum[8];
  int tid = threadIdx.x, lane = tid & 63, wid = tid >> 6;
  int v = (tid < B) ? btot[tid] : 0;
  int s = v;
#pragma unroll
  for (int off = 1; off < 64; off <<= 1) {
    int u = __shfl_up(s, off);
    if (lane >= off) s += u;
  }
  if (lane == 63) wsum[wid] = s;
  __syncthreads();
  if (tid == 0) {
    int run = 0;
#pragma unroll
    for (int w = 0; w < 8; ++w) { int t = wsum[w]; wsum[w] = run; run += t; }
  }
  __syncthreads();
  int excl = wsum[wid] + s - v;
  if (tid < B) bucket_start[tid] = excl;
  if (tid == 0) { bucket_start[B] = E; row_start[M] = E; }
}

__global__ __launch_bounds__(256) void bscatter_kernel(
    const int* __restrict__ rows, const int* __restrict__ cols,
    const float* __restrict__ vals, const int* __restrict__ c,
    const int* __restrict__ bucket_start, int2* __restrict__ binned,
    int E, int B, int ce) {
  __shared__ int base[BMAX];
  __shared__ int lcur[BMAX];
  int tid = threadIdx.x, blk = blockIdx.x;
  for (int b = tid; b < B; b += 256) {
    base[b] = bucket_start[b] + c[b * NBLK + blk];
    lcur[b] = 0;
  }
  __syncthreads();
  int start = blk * ce;
  int end = min(E, start + ce);
  for (int e = start + tid; e < end; e += 256) {
    int r = rows[e];
    int b = r >> 8;
    int pos = atomicAdd(&lcur[b], 1);
    binned[base[b] + pos] =
        make_int2(cols[e] | ((r & 255) << 17), __float_as_int(vals[e]));
  }
}

// one block per bucket: row-histogram -> scan (emits row_start) -> scatter
__global__ __launch_bounds__(256) void bsort_kernel(
    const int2* __restrict__ binned, const int* __restrict__ bucket_start,
    int2* __restrict__ csr, int* __restrict__ row_start, int M) {
  __shared__ int hist[256];
  __shared__ int wsum[4];
  int b = blockIdx.x, tid = threadIdx.x;
  int base = bucket_start[b];
  int cnt = bucket_start[b + 1] - base;
  hist[tid] = 0;
  __syncthreads();
  for (int i = tid; i < cnt; i += 256)
    atomicAdd(&hist[((unsigned)binned[base + i].x) >> 17], 1);
  __syncthreads();
  int v = hist[tid];
  int lane = tid & 63, wid = tid >> 6;
  int s = v;
#pragma unroll
  for (int off = 1; off < 64; off <<= 1) {
    int u = __shfl_up(s, off);
    if (lane >= off) s += u;
  }
  if (lane == 63) wsum[wid] = s;
  __syncthreads();
  if (tid == 0) {
    int run = 0;
#pragma unroll
    for (int w = 0; w < 4; ++w) { int t = wsum[w]; wsum[w] = run; run += t; }
  }
  __syncthreads();
  int excl = wsum[wid] + s - v;
  int r = (b << 8) + tid;
  if (r < M) row_start[r] = base + excl;
  __syncthreads();          // all threads have read their hist[tid]
  hist[tid] = excl;         // reuse as running cursor
  __syncthreads();
  for (int i = tid; i < cnt; i += 256) {
    int2 en = binned[base + i];
    int rl = ((unsigned)en.x) >> 17;
    int p = atomicAdd(&hist[rl], 1);
    csr[base + p] = make_int2(en.x & 0x1FFFF, en.y);
  }
}

// ---------------------------------------------------------------------------
// 3. SpMM (wave per row; scalar-pipe edges; bf16 gather, fp32 self term,
//    fp32 dst updated IN PLACE — fp32 is only ever read at the wave's own row)
// ---------------------------------------------------------------------------
__global__ __launch_bounds__(256) void spmm_kernel(
    float* __restrict__ Tf, const uint* __restrict__ srcb,
    const uint* __restrict__ prevb, uint* __restrict__ dstb,
    const int* __restrict__ row_start, const int2* __restrict__ csr,
    int M, float alpha, float beta, float gamma, int write_f32) {
  int wid = __builtin_amdgcn_readfirstlane((int)threadIdx.x >> 6);
  int gw = blockIdx.x * 4 + wid;
  int lane = threadIdx.x & 63;
  if (gw >= M) return;
  int s = row_start[gw];
  int e = row_start[gw + 1];
  float ax = 0.f, ay = 0.f;
  int j = s;
  for (; j + 8 <= e; j += 8) {
#pragma unroll
    for (int u = 0; u < 8; ++u) {
      int2 cv = csr[j + u];                              // uniform -> s_load
      uint p = srcb[(size_t)(unsigned)cv.x * 64 + lane]; // 256B row gather
      float v = __int_as_float(cv.y);
      ax += v * bf16_lo(p);
      ay += v * bf16_hi(p);
    }
  }
  for (; j < e; ++j) {
    int2 cv = csr[j];
    uint p = srcb[(size_t)(unsigned)cv.x * 64 + lane];
    float v = __int_as_float(cv.y);
    ax += v * bf16_lo(p);
    ay += v * bf16_hi(p);
  }
  float2 sv = reinterpret_cast<const float2*>(Tf)[(size_t)gw * 64 + lane];
  ax = alpha * ax + beta * sv.x;
  ay = alpha * ay + beta * sv.y;
  if (prevb) {
    uint pp = prevb[(size_t)gw * 64 + lane];
    ax += gamma * bf16_lo(pp);
    ay += gamma * bf16_hi(pp);
  }
  if (write_f32)
    reinterpret_cast<float2*>(Tf)[(size_t)gw * 64 + lane] = make_float2(ax, ay);
  dstb[(size_t)gw * 64 + lane] =
      (uint)f32_to_bf16_rn(ax) | ((uint)f32_to_bf16_rn(ay) << 16);
}

// ---------------------------------------------------------------------------
// 4. Final GEMM via MFMA 16x16x32 bf16, no LDS (round-4 proven).
// ---------------------------------------------------------------------------
__global__ __launch_bounds__(256) void gemm_kernel(
    const ushort* __restrict__ Tb0, const ushort* __restrict__ Tb1,
    const ushort* __restrict__ Tb2, const ushort* __restrict__ Tb3,
    const float* __restrict__ W, float* __restrict__ out,
    int M, int nwaves) {
  int lane = threadIdx.x & 63;
  int gwave = blockIdx.x * 4 + ((int)threadIdx.x >> 6);
  int g = lane >> 4;   // 0..3 (k-chunk group / store vertex)
  int q = lane & 15;   // A row within tile / output column within fo-tile

  bf16x8 b[4][4];
#pragma unroll
  for (int t = 0; t < 4; ++t) {
#pragma unroll
    for (int ft = 0; ft < 4; ++ft) {
#pragma unroll
      for (int e = 0; e < 8; ++e) {
        float w = W[(t * 32 + g * 8 + e) * FOUT + ft * 16 + q];
        b[t][ft][e] = (short)f32_to_bf16_rn(w);
      }
    }
  }

  int NT = (M + 3) >> 2;
  for (int tile = gwave; tile < NT; tile += nwaves) {
    int m0 = tile * 4;
    int mA = m0 + (q >> 2);
    if (mA > M - 1) mA = M - 1;
    int n = q & 3;
    size_t abase = (size_t)mA * ROWLEN + n;

    f32x4 C0 = {0.f, 0.f, 0.f, 0.f};
    f32x4 C1 = C0, C2 = C0, C3 = C0;
#pragma unroll
    for (int t = 0; t < 4; ++t) {
      int kc = t * 4 + g;
      bf16x8 a;
#pragma unroll
      for (int e = 0; e < 8; ++e) {
        int colT = (2 * kc + (e >> 2)) * 4;
        const ushort* Tb = (e & 3) == 0 ? Tb0 : (e & 3) == 1 ? Tb1
                         : (e & 3) == 2 ? Tb2 : Tb3;
        a[e] = (short)Tb[abase + colT];
      }
      C0 = __builtin_amdgcn_mfma_f32_16x16x32_bf16(a, b[t][0], C0, 0, 0, 0);
      C1 = __builtin_amdgcn_mfma_f32_16x16x32_bf16(a, b[t][1], C1, 0, 0, 0);
      C2 = __builtin_amdgcn_mfma_f32_16x16x32_bf16(a, b[t][2], C2, 0, 0, 0);
      C3 = __builtin_amdgcn_mfma_f32_16x16x32_bf16(a, b[t][3], C3, 0, 0, 0);
    }
    int mS = m0 + g;
    if (mS < M) {
#pragma unroll
      for (int r = 0; r < 4; ++r) {
        size_t ob = ((size_t)r * M + mS) * FOUT + q;
        out[ob +  0] = C0[r];
        out[ob + 16] = C1[r];
        out[ob + 32] = C2[r];
        out[ob + 48] = C3[r];
      }
    }
  }
}

// ---------------------------------------------------------------------------
extern "C" void kernel_launch(void* const* d_in, const int* in_sizes, int n_in,
                              void* d_out, int out_size, void* d_ws, size_t ws_size,
                              hipStream_t stream) {
  const float* x         = (const float*)d_in[0];
  const float* edge_vals = (const float*)d_in[1];
  const float* W         = (const float*)d_in[2];
  const int* edge_rows   = (const int*)d_in[3];
  const int* edge_cols   = (const int*)d_in[4];
  float* out = (float*)d_out;

  int M = in_sizes[0] / (N_DIM * FIN);
  int E = in_sizes[1];
  int MF = M * FIN;
  int B = (M + 255) >> 8;             // buckets of 256 rows
  int ce = (E + NBLK - 1) / NBLK;     // edges per chunk

  char* ws = (char*)d_ws;
  size_t rowf = (size_t)M * ROWLEN;
  float* Tf = (float*)ws;                                    // M*128*4
  ushort* Tb0 = (ushort*)(ws + rowf * sizeof(float));
  ushort* Tb1 = Tb0 + rowf;
  ushort* Tb2 = Tb1 + rowf;
  ushort* Tb3 = Tb2 + rowf;
  int2* binned = (int2*)(Tb3 + rowf);
  int2* csr = binned + E;
  int* c = (int*)(csr + E);            // B*NBLK
  int* btot = c + (size_t)B * NBLK;    // B
  int* bucket_start = btot + B;        // B+1
  int* row_start = bucket_start + (B + 1);  // M+1

  transpose_kernel<<<(MF + 255) / 256, 256, 0, stream>>>(x, Tf, Tb0, MF);
  bcount_kernel<<<NBLK, 256, 0, stream>>>(edge_rows, c, E, B, ce);
  bscanA_kernel<<<B, 256, 0, stream>>>(c, btot);
  bscanB_kernel<<<1, 512, 0, stream>>>(btot, bucket_start, row_start, B, M, E);
  bscatter_kernel<<<NBLK, 256, 0, stream>>>(edge_rows, edge_cols, edge_vals,
                                            c, bucket_start, binned, E, B, ce);
  bsort_kernel<<<B, 256, 0, stream>>>(binned, bucket_start, csr, row_start, M);

  int spmm_blocks = (M + 3) / 4;  // wave per row, 4 waves/block
  // T1 = L'T0:        1*gather(Tb0) - 1*Tf   (Tf: T0 -> T1 in place)
  spmm_kernel<<<spmm_blocks, 256, 0, stream>>>(
      Tf, (const uint*)Tb0, nullptr, (uint*)Tb1, row_start, csr,
      M, 1.f, -1.f, 0.f, 1);
  // T2 = 2L'T1 - T0:  2*gather(Tb1) - 2*Tf - 1*Tb0   (Tf: T1 -> T2)
  spmm_kernel<<<spmm_blocks, 256, 0, stream>>>(
      Tf, (const uint*)Tb1, (const uint*)Tb0, (uint*)Tb2, row_start, csr,
      M, 2.f, -2.f, -1.f, 1);
  // T3 = 2L'T2 - T1:  fp32 output not needed
  spmm_kernel<<<spmm_blocks, 256, 0, stream>>>(
      Tf, (const uint*)Tb2, (const uint*)Tb1, (uint*)Tb3, row_start, csr,
      M, 2.f, -2.f, -1.f, 0);

  int gemm_blocks = 1024;  // 4096 waves, grid-stride over (M+3)/4 tiles
  gemm_kernel<<<gemm_blocks, 256, 0, stream>>>(
      Tb0, Tb1, Tb2, Tb3, W, out, M, gemm_blocks * 4);
}

// Round 6
// 316.934 us; speedup vs baseline: 3.1103x; 1.1071x over previous
//
#include <hip/hip_runtime.h>
#include <hip/hip_bf16.h>
#include <stdint.h>

#define N_DIM 4
#define FIN 32
#define FOUT 64
#define ROWLEN 128   // FIN * N_DIM
#define NBLK 256     // edge chunks for the counting sort
#define BMAX 512     // max buckets (rows/256), M <= 131072

typedef __attribute__((ext_vector_type(4))) float f32x4;
typedef __attribute__((ext_vector_type(8))) short bf16x8;

__device__ __forceinline__ ushort f32_to_bf16_rn(float f) {
  uint u = __float_as_uint(f);
  u += 0x7FFFu + ((u >> 16) & 1u);     // round-to-nearest-even
  return (ushort)(u >> 16);
}
__device__ __forceinline__ float bf16_lo(uint p) { return __uint_as_float(p << 16); }
__device__ __forceinline__ float bf16_hi(uint p) { return __uint_as_float(p & 0xFFFF0000u); }

// ---------------------------------------------------------------------------
// 1. Transpose x[N][M][Fin] -> Tb0[m][n*32+f] (bf16).  Row layout is [n][f]
//    so the gemm A-fragment (fixed n, 8 consecutive f) is one dwordx4.
//    Thread i -> (m, n, f8): reads 8 consecutive f, writes ushort8.
// ---------------------------------------------------------------------------
__global__ void transpose_kernel(const float* __restrict__ x,
                                 ushort* __restrict__ Tb0, int M) {
  int i = blockIdx.x * blockDim.x + threadIdx.x;
  if (i >= M * 16) return;
  int m = i >> 4;
  int n = (i >> 2) & 3;
  int f8 = i & 3;
  const float* src = x + ((size_t)n * M + m) * FIN + f8 * 8;
  float4 v0 = *reinterpret_cast<const float4*>(src);
  float4 v1 = *reinterpret_cast<const float4*>(src + 4);
  ushort h[8];
  h[0] = f32_to_bf16_rn(v0.x); h[1] = f32_to_bf16_rn(v0.y);
  h[2] = f32_to_bf16_rn(v0.z); h[3] = f32_to_bf16_rn(v0.w);
  h[4] = f32_to_bf16_rn(v1.x); h[5] = f32_to_bf16_rn(v1.y);
  h[6] = f32_to_bf16_rn(v1.z); h[7] = f32_to_bf16_rn(v1.w);
  *reinterpret_cast<uint4*>(Tb0 + (size_t)m * ROWLEN + n * 32 + f8 * 8) =
      *reinterpret_cast<const uint4*>(h);
}

// ---------------------------------------------------------------------------
// 2. CSR build — two-level counting sort with block-private regions.
//    bucket = row >> 8 (256 rows); entry packed as (col | rowlow<<17, val).
// ---------------------------------------------------------------------------
__global__ __launch_bounds__(256) void bcount_kernel(
    const int* __restrict__ rows, int* __restrict__ c, int E, int B, int ce) {
  __shared__ int hist[BMAX];
  int tid = threadIdx.x, blk = blockIdx.x;
  for (int b = tid; b < B; b += 256) hist[b] = 0;
  __syncthreads();
  int start = blk * ce;
  int end = min(E, start + ce);
  for (int e = start + tid; e < end; e += 256)
    atomicAdd(&hist[rows[e] >> 8], 1);
  __syncthreads();
  for (int b = tid; b < B; b += 256) c[b * NBLK + blk] = hist[b];
}

// per-bucket exclusive scan over the 256 block counts (in place) + totals
__global__ __launch_bounds__(256) void bscanA_kernel(
    int* __restrict__ c, int* __restrict__ btot) {
  __shared__ int wsum[4];
  int b = blockIdx.x, tid = threadIdx.x;
  int lane = tid & 63, wid = tid >> 6;
  int v = c[b * NBLK + tid];
  int s = v;
#pragma unroll
  for (int off = 1; off < 64; off <<= 1) {
    int u = __shfl_up(s, off);
    if (lane >= off) s += u;
  }
  if (lane == 63) wsum[wid] = s;
  __syncthreads();
  if (tid == 0) {
    int run = 0;
#pragma unroll
    for (int w = 0; w < 4; ++w) { int t = wsum[w]; wsum[w] = run; run += t; }
  }
  __syncthreads();
  int excl = wsum[wid] + s - v;
  c[b * NBLK + tid] = excl;
  if (tid == 255) btot[b] = excl + v;
}

// scan bucket totals -> bucket_start (B <= 512, one 512-thread block)
__global__ __launch_bounds__(512) void bscanB_kernel(
    const int* __restrict__ btot, int* __restrict__ bucket_start,
    int* __restrict__ row_start, int B, int M, int E) {
  __shared__ int wsum[8];
  int tid = threadIdx.x, lane = tid & 63, wid = tid >> 6;
  int v = (tid < B) ? btot[tid] : 0;
  int s = v;
#pragma unroll
  for (int off = 1; off < 64; off <<= 1) {
    int u = __shfl_up(s, off);
    if (lane >= off) s += u;
  }
  if (lane == 63) wsum[wid] = s;
  __syncthreads();
  if (tid == 0) {
    int run = 0;
#pragma unroll
    for (int w = 0; w < 8; ++w) { int t = wsum[w]; wsum[w] = run; run += t; }
  }
  __syncthreads();
  int excl = wsum[wid] + s - v;
  if (tid < B) bucket_start[tid] = excl;
  if (tid == 0) { bucket_start[B] = E; row_start[M] = E; }
}

__global__ __launch_bounds__(256) void bscatter_kernel(
    const int* __restrict__ rows, const int* __restrict__ cols,
    const float* __restrict__ vals, const int* __restrict__ c,
    const int* __restrict__ bucket_start, int2* __restrict__ binned,
    int E, int B, int ce) {
  __shared__ int base[BMAX];
  __shared__ int lcur[BMAX];
  int tid = threadIdx.x, blk = blockIdx.x;
  for (int b = tid; b < B; b += 256) {
    base[b] = bucket_start[b] + c[b * NBLK + blk];
    lcur[b] = 0;
  }
  __syncthreads();
  int start = blk * ce;
  int end = min(E, start + ce);
  for (int e = start + tid; e < end; e += 256) {
    int r = rows[e];
    int b = r >> 8;
    int pos = atomicAdd(&lcur[b], 1);
    binned[base[b] + pos] =
        make_int2(cols[e] | ((r & 255) << 17), __float_as_int(vals[e]));
  }
}

// one block per bucket: row-histogram -> scan (emits row_start) -> scatter
__global__ __launch_bounds__(256) void bsort_kernel(
    const int2* __restrict__ binned, const int* __restrict__ bucket_start,
    int2* __restrict__ csr, int* __restrict__ row_start, int M) {
  __shared__ int hist[256];
  __shared__ int wsum[4];
  int b = blockIdx.x, tid = threadIdx.x;
  int base = bucket_start[b];
  int cnt = bucket_start[b + 1] - base;
  hist[tid] = 0;
  __syncthreads();
  for (int i = tid; i < cnt; i += 256)
    atomicAdd(&hist[((unsigned)binned[base + i].x) >> 17], 1);
  __syncthreads();
  int v = hist[tid];
  int lane = tid & 63, wid = tid >> 6;
  int s = v;
#pragma unroll
  for (int off = 1; off < 64; off <<= 1) {
    int u = __shfl_up(s, off);
    if (lane >= off) s += u;
  }
  if (lane == 63) wsum[wid] = s;
  __syncthreads();
  if (tid == 0) {
    int run = 0;
#pragma unroll
    for (int w = 0; w < 4; ++w) { int t = wsum[w]; wsum[w] = run; run += t; }
  }
  __syncthreads();
  int excl = wsum[wid] + s - v;
  int r = (b << 8) + tid;
  if (r < M) row_start[r] = base + excl;
  __syncthreads();          // all threads have read their hist[tid]
  hist[tid] = excl;         // reuse as running cursor
  __syncthreads();
  for (int i = tid; i < cnt; i += 256) {
    int2 en = binned[base + i];
    int rl = ((unsigned)en.x) >> 17;
    int p = atomicAdd(&hist[rl], 1);
    csr[base + p] = make_int2(en.x & 0x1FFFF, en.y);
  }
}

// ---------------------------------------------------------------------------
// 3. SpMM (wave per row; scalar-pipe edges; all-bf16 operands, fp32 accum):
//    dstb[m,:] = bf16( alpha*Sum val*srcb[col] + beta*srcb[m] + gamma*prevb[m] )
// ---------------------------------------------------------------------------
__global__ __launch_bounds__(256) void spmm_kernel(
    const uint* __restrict__ srcb, const uint* __restrict__ prevb,
    uint* __restrict__ dstb,
    const int* __restrict__ row_start, const int2* __restrict__ csr,
    int M, float alpha, float beta, float gamma) {
  int wid = __builtin_amdgcn_readfirstlane((int)threadIdx.x >> 6);
  int gw = blockIdx.x * 4 + wid;
  int lane = threadIdx.x & 63;
  if (gw >= M) return;
  int s = row_start[gw];
  int e = row_start[gw + 1];
  float ax = 0.f, ay = 0.f;
  int j = s;
  for (; j + 8 <= e; j += 8) {
#pragma unroll
    for (int u = 0; u < 8; ++u) {
      int2 cv = csr[j + u];                              // uniform -> s_load
      uint p = srcb[(size_t)(unsigned)cv.x * 64 + lane]; // 256B row gather
      float v = __int_as_float(cv.y);
      ax += v * bf16_lo(p);
      ay += v * bf16_hi(p);
    }
  }
  for (; j < e; ++j) {
    int2 cv = csr[j];
    uint p = srcb[(size_t)(unsigned)cv.x * 64 + lane];
    float v = __int_as_float(cv.y);
    ax += v * bf16_lo(p);
    ay += v * bf16_hi(p);
  }
  uint sp = srcb[(size_t)gw * 64 + lane];
  ax = alpha * ax + beta * bf16_lo(sp);
  ay = alpha * ay + beta * bf16_hi(sp);
  if (prevb) {
    uint pp = prevb[(size_t)gw * 64 + lane];
    ax += gamma * bf16_lo(pp);
    ay += gamma * bf16_hi(pp);
  }
  dstb[(size_t)gw * 64 + lane] =
      (uint)f32_to_bf16_rn(ax) | ((uint)f32_to_bf16_rn(ay) << 16);
}

// ---------------------------------------------------------------------------
// 4. Final GEMM via MFMA 16x16x32 bf16, no LDS.
//    XS[row=(m,n)][kappa=t*32+f] = Tb_t[m][n*32+f]  (kappa is a permutation
//    of the contraction index, applied to BOTH operands: W row = f*4 + t).
//    A-fragment per t: ONE 16B load (8 consecutive f at fixed n).
// ---------------------------------------------------------------------------
__global__ __launch_bounds__(256) void gemm_kernel(
    const ushort* __restrict__ Tb0, const ushort* __restrict__ Tb1,
    const ushort* __restrict__ Tb2, const ushort* __restrict__ Tb3,
    const float* __restrict__ W, float* __restrict__ out,
    int M, int nwaves) {
  int lane = threadIdx.x & 63;
  int gwave = blockIdx.x * 4 + ((int)threadIdx.x >> 6);
  int g = lane >> 4;   // 0..3: kappa-chunk group / store vertex
  int q = lane & 15;   // A row within tile / output column within fo-tile

  // b[t][ft][e] = bf16(W[(8g+e)*4 + t][ft*16 + q])   (kappa = t*32 + 8g + e)
  bf16x8 b[4][4];
#pragma unroll
  for (int t = 0; t < 4; ++t) {
#pragma unroll
    for (int ft = 0; ft < 4; ++ft) {
#pragma unroll
      for (int e = 0; e < 8; ++e) {
        float w = W[((8 * g + e) * 4 + t) * FOUT + ft * 16 + q];
        b[t][ft][e] = (short)f32_to_bf16_rn(w);
      }
    }
  }

  int NT = (M + 3) >> 2;
  for (int tile = gwave; tile < NT; tile += nwaves) {
    int m0 = tile * 4;
    int mA = m0 + (q >> 2);
    if (mA > M - 1) mA = M - 1;      // clamp; garbage rows are store-guarded
    int n = q & 3;
    size_t abase = (size_t)mA * ROWLEN + n * 32 + g * 8;

    f32x4 C0 = {0.f, 0.f, 0.f, 0.f};
    f32x4 C1 = C0, C2 = C0, C3 = C0;
#pragma unroll
    for (int t = 0; t < 4; ++t) {
      const ushort* Tb = t == 0 ? Tb0 : t == 1 ? Tb1 : t == 2 ? Tb2 : Tb3;
      bf16x8 a = *reinterpret_cast<const bf16x8*>(Tb + abase);  // 16B aligned
      C0 = __builtin_amdgcn_mfma_f32_16x16x32_bf16(a, b[t][0], C0, 0, 0, 0);
      C1 = __builtin_amdgcn_mfma_f32_16x16x32_bf16(a, b[t][1], C1, 0, 0, 0);
      C2 = __builtin_amdgcn_mfma_f32_16x16x32_bf16(a, b[t][2], C2, 0, 0, 0);
      C3 = __builtin_amdgcn_mfma_f32_16x16x32_bf16(a, b[t][3], C3, 0, 0, 0);
    }
    // C mapping: col = q, row = g*4 + r  ->  vertex m0+g, n = r
    int mS = m0 + g;
    if (mS < M) {
#pragma unroll
      for (int r = 0; r < 4; ++r) {
        size_t ob = ((size_t)r * M + mS) * FOUT + q;
        out[ob +  0] = C0[r];
        out[ob + 16] = C1[r];
        out[ob + 32] = C2[r];
        out[ob + 48] = C3[r];
      }
    }
  }
}

// ---------------------------------------------------------------------------
extern "C" void kernel_launch(void* const* d_in, const int* in_sizes, int n_in,
                              void* d_out, int out_size, void* d_ws, size_t ws_size,
                              hipStream_t stream) {
  const float* x         = (const float*)d_in[0];
  const float* edge_vals = (const float*)d_in[1];
  const float* W         = (const float*)d_in[2];
  const int* edge_rows   = (const int*)d_in[3];
  const int* edge_cols   = (const int*)d_in[4];
  float* out = (float*)d_out;

  int M = in_sizes[0] / (N_DIM * FIN);
  int E = in_sizes[1];
  int B = (M + 255) >> 8;             // buckets of 256 rows
  int ce = (E + NBLK - 1) / NBLK;     // edges per chunk

  char* ws = (char*)d_ws;
  size_t rowf = (size_t)M * ROWLEN;
  ushort* Tb0 = (ushort*)ws;
  ushort* Tb1 = Tb0 + rowf;
  ushort* Tb2 = Tb1 + rowf;
  ushort* Tb3 = Tb2 + rowf;
  int2* binned = (int2*)(Tb3 + rowf);       // 4*rowf*2 bytes offset, 8B-aligned
  int2* csr = binned + E;
  int* c = (int*)(csr + E);                 // B*NBLK
  int* btot = c + (size_t)B * NBLK;         // B
  int* bucket_start = btot + B;             // B+1
  int* row_start = bucket_start + (B + 1);  // M+1

  transpose_kernel<<<(M * 16 + 255) / 256, 256, 0, stream>>>(x, Tb0, M);
  bcount_kernel<<<NBLK, 256, 0, stream>>>(edge_rows, c, E, B, ce);
  bscanA_kernel<<<B, 256, 0, stream>>>(c, btot);
  bscanB_kernel<<<1, 512, 0, stream>>>(btot, bucket_start, row_start, B, M, E);
  bscatter_kernel<<<NBLK, 256, 0, stream>>>(edge_rows, edge_cols, edge_vals,
                                            c, bucket_start, binned, E, B, ce);
  bsort_kernel<<<B, 256, 0, stream>>>(binned, bucket_start, csr, row_start, M);

  int spmm_blocks = (M + 3) / 4;  // wave per row, 4 waves/block
  // T1 = L'T0
  spmm_kernel<<<spmm_blocks, 256, 0, stream>>>(
      (const uint*)Tb0, nullptr, (uint*)Tb1, row_start, csr,
      M, 1.f, -1.f, 0.f);
  // T2 = 2L'T1 - T0
  spmm_kernel<<<spmm_blocks, 256, 0, stream>>>(
      (const uint*)Tb1, (const uint*)Tb0, (uint*)Tb2, row_start, csr,
      M, 2.f, -2.f, -1.f);
  // T3 = 2L'T2 - T1
  spmm_kernel<<<spmm_blocks, 256, 0, stream>>>(
      (const uint*)Tb2, (const uint*)Tb1, (uint*)Tb3, row_start, csr,
      M, 2.f, -2.f, -1.f);

  int gemm_blocks = 1024;  // 4096 waves, grid-stride over (M+3)/4 tiles
  gemm_kernel<<<gemm_blocks, 256, 0, stream>>>(
      Tb0, Tb1, Tb2, Tb3, W, out, M, gemm_blocks * 4);
}

// Round 7
// 309.454 us; speedup vs baseline: 3.1855x; 1.0242x over previous
//
#include <hip/hip_runtime.h>
#include <hip/hip_bf16.h>
#include <stdint.h>

#define N_DIM 4
#define FIN 32
#define FOUT 64
#define ROWLEN 128   // FIN * N_DIM
#define NBLK 256     // edge chunks for the counting sort
#define BMAX 512     // max buckets (rows/256), M <= 131072

typedef __attribute__((ext_vector_type(4))) float f32x4;
typedef __attribute__((ext_vector_type(8))) short bf16x8;

__device__ __forceinline__ ushort f32_to_bf16_rn(float f) {
  uint u = __float_as_uint(f);
  u += 0x7FFFu + ((u >> 16) & 1u);     // round-to-nearest-even
  return (ushort)(u >> 16);
}
__device__ __forceinline__ float bf16_lo(uint p) { return __uint_as_float(p << 16); }
__device__ __forceinline__ float bf16_hi(uint p) { return __uint_as_float(p & 0xFFFF0000u); }

// ---------------------------------------------------------------------------
// 1. Transpose x[N][M][Fin] -> Tb0[m][n*32+f] (bf16).
// ---------------------------------------------------------------------------
__global__ void transpose_kernel(const float* __restrict__ x,
                                 ushort* __restrict__ Tb0, int M) {
  int i = blockIdx.x * blockDim.x + threadIdx.x;
  if (i >= M * 16) return;
  int m = i >> 4;
  int n = (i >> 2) & 3;
  int f8 = i & 3;
  const float* src = x + ((size_t)n * M + m) * FIN + f8 * 8;
  float4 v0 = *reinterpret_cast<const float4*>(src);
  float4 v1 = *reinterpret_cast<const float4*>(src + 4);
  ushort h[8];
  h[0] = f32_to_bf16_rn(v0.x); h[1] = f32_to_bf16_rn(v0.y);
  h[2] = f32_to_bf16_rn(v0.z); h[3] = f32_to_bf16_rn(v0.w);
  h[4] = f32_to_bf16_rn(v1.x); h[5] = f32_to_bf16_rn(v1.y);
  h[6] = f32_to_bf16_rn(v1.z); h[7] = f32_to_bf16_rn(v1.w);
  *reinterpret_cast<uint4*>(Tb0 + (size_t)m * ROWLEN + n * 32 + f8 * 8) =
      *reinterpret_cast<const uint4*>(h);
}

// ---------------------------------------------------------------------------
// 2. CSR build — two-level counting sort with block-private regions.
// ---------------------------------------------------------------------------
__global__ __launch_bounds__(256) void bcount_kernel(
    const int* __restrict__ rows, int* __restrict__ c, int E, int B, int ce) {
  __shared__ int hist[BMAX];
  int tid = threadIdx.x, blk = blockIdx.x;
  for (int b = tid; b < B; b += 256) hist[b] = 0;
  __syncthreads();
  int start = blk * ce;
  int end = min(E, start + ce);
  for (int e = start + tid; e < end; e += 256)
    atomicAdd(&hist[rows[e] >> 8], 1);
  __syncthreads();
  for (int b = tid; b < B; b += 256) c[b * NBLK + blk] = hist[b];
}

__global__ __launch_bounds__(256) void bscanA_kernel(
    int* __restrict__ c, int* __restrict__ btot) {
  __shared__ int wsum[4];
  int b = blockIdx.x, tid = threadIdx.x;
  int lane = tid & 63, wid = tid >> 6;
  int v = c[b * NBLK + tid];
  int s = v;
#pragma unroll
  for (int off = 1; off < 64; off <<= 1) {
    int u = __shfl_up(s, off);
    if (lane >= off) s += u;
  }
  if (lane == 63) wsum[wid] = s;
  __syncthreads();
  if (tid == 0) {
    int run = 0;
#pragma unroll
    for (int w = 0; w < 4; ++w) { int t = wsum[w]; wsum[w] = run; run += t; }
  }
  __syncthreads();
  int excl = wsum[wid] + s - v;
  c[b * NBLK + tid] = excl;
  if (tid == 255) btot[b] = excl + v;
}

__global__ __launch_bounds__(512) void bscanB_kernel(
    const int* __restrict__ btot, int* __restrict__ bucket_start,
    int* __restrict__ row_start, int B, int M, int E) {
  __shared__ int wsum[8];
  int tid = threadIdx.x, lane = tid & 63, wid = tid >> 6;
  int v = (tid < B) ? btot[tid] : 0;
  int s = v;
#pragma unroll
  for (int off = 1; off < 64; off <<= 1) {
    int u = __shfl_up(s, off);
    if (lane >= off) s += u;
  }
  if (lane == 63) wsum[wid] = s;
  __syncthreads();
  if (tid == 0) {
    int run = 0;
#pragma unroll
    for (int w = 0; w < 8; ++w) { int t = wsum[w]; wsum[w] = run; run += t; }
  }
  __syncthreads();
  int excl = wsum[wid] + s - v;
  if (tid < B) bucket_start[tid] = excl;
  if (tid == 0) { bucket_start[B] = E; row_start[M] = E; }
}

__global__ __launch_bounds__(256) void bscatter_kernel(
    const int* __restrict__ rows, const int* __restrict__ cols,
    const float* __restrict__ vals, const int* __restrict__ c,
    const int* __restrict__ bucket_start, int2* __restrict__ binned,
    int E, int B, int ce) {
  __shared__ int base[BMAX];
  __shared__ int lcur[BMAX];
  int tid = threadIdx.x, blk = blockIdx.x;
  for (int b = tid; b < B; b += 256) {
    base[b] = bucket_start[b] + c[b * NBLK + blk];
    lcur[b] = 0;
  }
  __syncthreads();
  int start = blk * ce;
  int end = min(E, start + ce);
  for (int e = start + tid; e < end; e += 256) {
    int r = rows[e];
    int b = r >> 8;
    int pos = atomicAdd(&lcur[b], 1);
    binned[base[b] + pos] =
        make_int2(cols[e] | ((r & 255) << 17), __float_as_int(vals[e]));
  }
}

__global__ __launch_bounds__(256) void bsort_kernel(
    const int2* __restrict__ binned, const int* __restrict__ bucket_start,
    int2* __restrict__ csr, int* __restrict__ row_start, int M) {
  __shared__ int hist[256];
  __shared__ int wsum[4];
  int b = blockIdx.x, tid = threadIdx.x;
  int base = bucket_start[b];
  int cnt = bucket_start[b + 1] - base;
  hist[tid] = 0;
  __syncthreads();
  for (int i = tid; i < cnt; i += 256)
    atomicAdd(&hist[((unsigned)binned[base + i].x) >> 17], 1);
  __syncthreads();
  int v = hist[tid];
  int lane = tid & 63, wid = tid >> 6;
  int s = v;
#pragma unroll
  for (int off = 1; off < 64; off <<= 1) {
    int u = __shfl_up(s, off);
    if (lane >= off) s += u;
  }
  if (lane == 63) wsum[wid] = s;
  __syncthreads();
  if (tid == 0) {
    int run = 0;
#pragma unroll
    for (int w = 0; w < 4; ++w) { int t = wsum[w]; wsum[w] = run; run += t; }
  }
  __syncthreads();
  int excl = wsum[wid] + s - v;
  int r = (b << 8) + tid;
  if (r < M) row_start[r] = base + excl;
  __syncthreads();
  hist[tid] = excl;
  __syncthreads();
  for (int i = tid; i < cnt; i += 256) {
    int2 en = binned[base + i];
    int rl = ((unsigned)en.x) >> 17;
    int p = atomicAdd(&hist[rl], 1);
    csr[base + p] = make_int2(en.x & 0x1FFFF, en.y);
  }
}

// ---------------------------------------------------------------------------
// 3. SpMM (wave per row; scalar-pipe edges; 2x8-edge batches in flight):
//    dstb[m,:] = bf16( alpha*Sum val*srcb[col] + beta*srcb[m] + gamma*prevb[m] )
// ---------------------------------------------------------------------------
#define LOADC(C, base)                                        \
  _Pragma("unroll") for (int u = 0; u < 8; ++u) C[u] = csr[(base) + u];
#define GATH(G, C)                                            \
  _Pragma("unroll") for (int u = 0; u < 8; ++u)               \
      G[u] = srcb[(size_t)(unsigned)C[u].x * 64 + lane];
#define CONS(G, C)                                            \
  _Pragma("unroll") for (int u = 0; u < 8; ++u) {             \
    float v = __int_as_float(C[u].y);                         \
    ax += v * bf16_lo(G[u]);                                  \
    ay += v * bf16_hi(G[u]);                                  \
  }

__global__ __launch_bounds__(256) void spmm_kernel(
    const uint* __restrict__ srcb, const uint* __restrict__ prevb,
    uint* __restrict__ dstb,
    const int* __restrict__ row_start, const int2* __restrict__ csr,
    int M, float alpha, float beta, float gamma) {
  int wid = __builtin_amdgcn_readfirstlane((int)threadIdx.x >> 6);
  int gw = blockIdx.x * 4 + wid;
  int lane = threadIdx.x & 63;
  if (gw >= M) return;
  int s = row_start[gw];
  int e = row_start[gw + 1];
  // self/prev row loads issued up front (independent of the edge loop)
  uint sp = srcb[(size_t)gw * 64 + lane];
  uint pp = prevb ? prevb[(size_t)gw * 64 + lane] : 0u;

  float ax = 0.f, ay = 0.f;
  int j = s;
  int cnt = e - s;
  if (cnt >= 16) {
    int2 c0[8], c1[8];
    uint g0[8], g1[8];
    LOADC(c0, j); GATH(g0, c0);
    LOADC(c1, j + 8); GATH(g1, c1);
    j += 16;
    for (; j + 16 <= e; j += 16) {
      CONS(g0, c0); LOADC(c0, j); GATH(g0, c0);
      CONS(g1, c1); LOADC(c1, j + 8); GATH(g1, c1);
    }
    if (j + 8 <= e) {
      CONS(g0, c0); LOADC(c0, j); GATH(g0, c0);
      j += 8;
      CONS(g1, c1);
      CONS(g0, c0);
    } else {
      CONS(g0, c0);
      CONS(g1, c1);
    }
  } else if (cnt >= 8) {
    int2 c0[8];
    uint g0[8];
    LOADC(c0, j); GATH(g0, c0);
    j += 8;
    CONS(g0, c0);
  }
  for (; j < e; ++j) {
    int2 cv = csr[j];
    uint p = srcb[(size_t)(unsigned)cv.x * 64 + lane];
    float v = __int_as_float(cv.y);
    ax += v * bf16_lo(p);
    ay += v * bf16_hi(p);
  }

  ax = alpha * ax + beta * bf16_lo(sp);
  ay = alpha * ay + beta * bf16_hi(sp);
  if (prevb) {
    ax += gamma * bf16_lo(pp);
    ay += gamma * bf16_hi(pp);
  }
  dstb[(size_t)gw * 64 + lane] =
      (uint)f32_to_bf16_rn(ax) | ((uint)f32_to_bf16_rn(ay) << 16);
}

// ---------------------------------------------------------------------------
// 4. Final GEMM via MFMA 16x16x32 bf16, no LDS (round-6 proven).
// ---------------------------------------------------------------------------
__global__ __launch_bounds__(256) void gemm_kernel(
    const ushort* __restrict__ Tb0, const ushort* __restrict__ Tb1,
    const ushort* __restrict__ Tb2, const ushort* __restrict__ Tb3,
    const float* __restrict__ W, float* __restrict__ out,
    int M, int nwaves) {
  int lane = threadIdx.x & 63;
  int gwave = blockIdx.x * 4 + ((int)threadIdx.x >> 6);
  int g = lane >> 4;   // 0..3: kappa-chunk group / store vertex
  int q = lane & 15;   // A row within tile / output column within fo-tile

  // b[t][ft][e] = bf16(W[(8g+e)*4 + t][ft*16 + q])   (kappa = t*32 + 8g + e)
  bf16x8 b[4][4];
#pragma unroll
  for (int t = 0; t < 4; ++t) {
#pragma unroll
    for (int ft = 0; ft < 4; ++ft) {
#pragma unroll
      for (int e = 0; e < 8; ++e) {
        float w = W[((8 * g + e) * 4 + t) * FOUT + ft * 16 + q];
        b[t][ft][e] = (short)f32_to_bf16_rn(w);
      }
    }
  }

  int NT = (M + 3) >> 2;
  for (int tile = gwave; tile < NT; tile += nwaves) {
    int m0 = tile * 4;
    int mA = m0 + (q >> 2);
    if (mA > M - 1) mA = M - 1;      // clamp; garbage rows are store-guarded
    int n = q & 3;
    size_t abase = (size_t)mA * ROWLEN + n * 32 + g * 8;

    f32x4 C0 = {0.f, 0.f, 0.f, 0.f};
    f32x4 C1 = C0, C2 = C0, C3 = C0;
#pragma unroll
    for (int t = 0; t < 4; ++t) {
      const ushort* Tb = t == 0 ? Tb0 : t == 1 ? Tb1 : t == 2 ? Tb2 : Tb3;
      bf16x8 a = *reinterpret_cast<const bf16x8*>(Tb + abase);  // 16B aligned
      C0 = __builtin_amdgcn_mfma_f32_16x16x32_bf16(a, b[t][0], C0, 0, 0, 0);
      C1 = __builtin_amdgcn_mfma_f32_16x16x32_bf16(a, b[t][1], C1, 0, 0, 0);
      C2 = __builtin_amdgcn_mfma_f32_16x16x32_bf16(a, b[t][2], C2, 0, 0, 0);
      C3 = __builtin_amdgcn_mfma_f32_16x16x32_bf16(a, b[t][3], C3, 0, 0, 0);
    }
    int mS = m0 + g;
    if (mS < M) {
#pragma unroll
      for (int r = 0; r < 4; ++r) {
        size_t ob = ((size_t)r * M + mS) * FOUT + q;
        out[ob +  0] = C0[r];
        out[ob + 16] = C1[r];
        out[ob + 32] = C2[r];
        out[ob + 48] = C3[r];
      }
    }
  }
}

// ---------------------------------------------------------------------------
extern "C" void kernel_launch(void* const* d_in, const int* in_sizes, int n_in,
                              void* d_out, int out_size, void* d_ws, size_t ws_size,
                              hipStream_t stream) {
  const float* x         = (const float*)d_in[0];
  const float* edge_vals = (const float*)d_in[1];
  const float* W         = (const float*)d_in[2];
  const int* edge_rows   = (const int*)d_in[3];
  const int* edge_cols   = (const int*)d_in[4];
  float* out = (float*)d_out;

  int M = in_sizes[0] / (N_DIM * FIN);
  int E = in_sizes[1];
  int B = (M + 255) >> 8;             // buckets of 256 rows
  int ce = (E + NBLK - 1) / NBLK;     // edges per chunk

  char* ws = (char*)d_ws;
  size_t rowf = (size_t)M * ROWLEN;
  ushort* Tb0 = (ushort*)ws;
  ushort* Tb1 = Tb0 + rowf;
  ushort* Tb2 = Tb1 + rowf;
  ushort* Tb3 = Tb2 + rowf;
  int2* binned = (int2*)(Tb3 + rowf);
  int2* csr = binned + E;
  int* c = (int*)(csr + E);                 // B*NBLK
  int* btot = c + (size_t)B * NBLK;         // B
  int* bucket_start = btot + B;             // B+1
  int* row_start = bucket_start + (B + 1);  // M+1

  transpose_kernel<<<(M * 16 + 255) / 256, 256, 0, stream>>>(x, Tb0, M);
  bcount_kernel<<<NBLK, 256, 0, stream>>>(edge_rows, c, E, B, ce);
  bscanA_kernel<<<B, 256, 0, stream>>>(c, btot);
  bscanB_kernel<<<1, 512, 0, stream>>>(btot, bucket_start, row_start, B, M, E);
  bscatter_kernel<<<NBLK, 256, 0, stream>>>(edge_rows, edge_cols, edge_vals,
                                            c, bucket_start, binned, E, B, ce);
  bsort_kernel<<<B, 256, 0, stream>>>(binned, bucket_start, csr, row_start, M);

  int spmm_blocks = (M + 3) / 4;  // wave per row, 4 waves/block
  // T1 = L'T0
  spmm_kernel<<<spmm_blocks, 256, 0, stream>>>(
      (const uint*)Tb0, nullptr, (uint*)Tb1, row_start, csr,
      M, 1.f, -1.f, 0.f);
  // T2 = 2L'T1 - T0
  spmm_kernel<<<spmm_blocks, 256, 0, stream>>>(
      (const uint*)Tb1, (const uint*)Tb0, (uint*)Tb2, row_start, csr,
      M, 2.f, -2.f, -1.f);
  // T3 = 2L'T2 - T1
  spmm_kernel<<<spmm_blocks, 256, 0, stream>>>(
      (const uint*)Tb2, (const uint*)Tb1, (uint*)Tb3, row_start, csr,
      M, 2.f, -2.f, -1.f);

  int gemm_blocks = 1024;  // 4096 waves, grid-stride over (M+3)/4 tiles
  gemm_kernel<<<gemm_blocks, 256, 0, stream>>>(
      Tb0, Tb1, Tb2, Tb3, W, out, M, gemm_blocks * 4);
}